// Round 11
// baseline (309.517 us; speedup 1.0000x reference)
//
#include <hip/hip_runtime.h>
#include <math.h>

#define NFFT 4096
#define T    256
#define ROWS 4096
#define NX   1024
#define OUTN 2048
#define OFF  255

__device__ __forceinline__ float2 cmulf(float2 a, float2 b) {
  return make_float2(a.x * b.x - a.y * b.y, a.x * b.y + a.y * b.x);
}
__device__ __forceinline__ float2 caddf(float2 a, float2 b) {
  return make_float2(a.x + b.x, a.y + b.y);
}
__device__ __forceinline__ float2 csubf(float2 a, float2 b) {
  return make_float2(a.x - b.x, a.y - b.y);
}
// a * w (DIR=+1) or a * conj(w) (DIR=-1); same instruction count either way.
template <int DIR> __device__ __forceinline__ float2 tmul(float2 a, float2 w) {
  return (DIR > 0) ? make_float2(a.x * w.x - a.y * w.y, a.x * w.y + a.y * w.x)
                   : make_float2(a.x * w.x + a.y * w.y, a.y * w.x - a.x * w.y);
}
// multiply by -i (fwd) / +i (inv)
template <int DIR> __device__ __forceinline__ float2 mulmi(float2 a) {
  return (DIR > 0) ? make_float2(a.y, -a.x) : make_float2(-a.y, a.x);
}
// multiply by constant twiddle in FORWARD convention; conj for inverse
template <int DIR> __device__ __forceinline__ float2 cmulc(float2 a, float wr, float wi) {
  const float y = (DIR > 0) ? wi : -wi;
  return make_float2(a.x * wr - a.y * y, a.x * y + a.y * wr);
}

#define C16 0.9238795325112867f
#define S16 0.3826834323650898f
#define RH  0.7071067811865476f

// 16-pt DFT, natural order in/out: o[c] = sum_m v[m] W16^{mc} (conj for DIR=-1).
template <int DIR>
__device__ __forceinline__ void dft16(const float2* v, float2* o) {
  float2 f[16];
#pragma unroll
  for (int r = 0; r < 4; ++r) {
    const float2 a = v[r], b = v[r + 4], c = v[r + 8], d = v[r + 12];
    const float2 apc = caddf(a, c), amc = csubf(a, c);
    const float2 bpd = caddf(b, d), bmd = csubf(b, d);
    const float2 jb = mulmi<DIR>(bmd);
    f[r]      = caddf(apc, bpd);
    f[r + 4]  = caddf(amc, jb);
    f[r + 8]  = csubf(apc, bpd);
    f[r + 12] = csubf(amc, jb);
  }
  f[5]  = cmulc<DIR>(f[5],  C16, -S16);
  f[6]  = cmulc<DIR>(f[6],  RH,  -RH);
  f[7]  = cmulc<DIR>(f[7],  S16, -C16);
  f[9]  = cmulc<DIR>(f[9],  RH,  -RH);
  f[10] = mulmi<DIR>(f[10]);
  f[11] = cmulc<DIR>(f[11], -RH, -RH);
  f[13] = cmulc<DIR>(f[13], S16, -C16);
  f[14] = cmulc<DIR>(f[14], -RH, -RH);
  f[15] = cmulc<DIR>(f[15], -C16, S16);
#pragma unroll
  for (int c4 = 0; c4 < 4; ++c4) {
    const float2 a = f[4 * c4], b = f[4 * c4 + 1], c = f[4 * c4 + 2], d = f[4 * c4 + 3];
    const float2 apc = caddf(a, c), amc = csubf(a, c);
    const float2 bpd = caddf(b, d), bmd = csubf(b, d);
    const float2 jb = mulmi<DIR>(bmd);
    o[c4]      = caddf(apc, bpd);
    o[c4 + 4]  = caddf(amc, jb);
    o[c4 + 8]  = csubf(apc, bpd);
    o[c4 + 12] = csubf(amc, jb);
  }
}

// 16-pt DFT with only v[0..3] nonzero (zero-padded input).
template <int DIR>
__device__ __forceinline__ void dft16_sp4(const float2* v, float2* o) {
#pragma unroll
  for (int c4 = 0; c4 < 4; ++c4) {
    const float2 a = v[0];
    const float2 b = (c4 == 0) ? v[1]
                   : (c4 == 1) ? cmulc<DIR>(v[1], C16, -S16)
                   : (c4 == 2) ? cmulc<DIR>(v[1], RH, -RH)
                               : cmulc<DIR>(v[1], S16, -C16);
    const float2 c = (c4 == 0) ? v[2]
                   : (c4 == 1) ? cmulc<DIR>(v[2], RH, -RH)
                   : (c4 == 2) ? mulmi<DIR>(v[2])
                               : cmulc<DIR>(v[2], -RH, -RH);
    const float2 d = (c4 == 0) ? v[3]
                   : (c4 == 1) ? cmulc<DIR>(v[3], S16, -C16)
                   : (c4 == 2) ? cmulc<DIR>(v[3], -RH, -RH)
                               : cmulc<DIR>(v[3], -C16, S16);
    const float2 apc = caddf(a, c), amc = csubf(a, c);
    const float2 bpd = caddf(b, d), bmd = csubf(b, d);
    const float2 jb = mulmi<DIR>(bmd);
    o[c4]      = caddf(apc, bpd);
    o[c4 + 4]  = caddf(amc, jb);
    o[c4 + 8]  = csubf(apc, bpd);
    o[c4 + 12] = csubf(amc, jb);
  }
}

// Init: G[f] = W0(f)^2 * WL(f) / 4096 (IFFT scale folded);
// tw[n] = exp(-2*pi*i*n/4096), n < 4096. Recomputed every launch (ws poisoned).
__global__ __launch_bounds__(256) void init_tables(
    const float* __restrict__ w0r, const float* __restrict__ w0i,
    const float* __restrict__ wlr, const float* __restrict__ wli,
    float2* __restrict__ G, float2* __restrict__ tw) {
  const int f = blockIdx.x * blockDim.x + threadIdx.x;
  if (f >= NFFT) return;
  const float cconst = -2.0f * 3.14159265358979323846f / (float)NFFT;
  float w0re = 0.f, w0im = 0.f;
  for (int n = 0; n < 129; ++n) {
    const int mfn = (f * n) & (NFFT - 1);
    float sv, cv;
    __sincosf(cconst * (float)mfn, &sv, &cv);
    const float ar = w0r[n], ai = w0i[n];
    w0re += ar * cv - ai * sv;
    w0im += ar * sv + ai * cv;
  }
  float wlre = 0.f, wlim = 0.f;
  for (int n = 0; n < 257; ++n) {
    const int mfn = (f * n) & (NFFT - 1);
    float sv, cv;
    __sincosf(cconst * (float)mfn, &sv, &cv);
    const float ar = wlr[n], ai = wli[n];
    wlre += ar * cv - ai * sv;
    wlim += ar * sv + ai * cv;
  }
  const float2 W0 = make_float2(w0re, w0im);
  const float2 WL = make_float2(wlre, wlim);
  const float2 g = cmulf(cmulf(W0, W0), WL);
  G[f] = make_float2(g.x * (1.0f / NFFT), g.y * (1.0f / NFFT));
  float sv, cv;
  __sincosf(cconst * (float)f, &sv, &cv);
  tw[f] = make_float2(cv, sv);
}

// Register-resident 16^3 FFT, 256 threads, 16 float2/thread.
// LDS = 16*256*8 = 32768 B exactly -> 5 blocks/CU (20 waves).
// ex2 uses low-nibble XOR swizzle (addr = row*256 + (pos ^ row)) instead of
// 257-padding: all 4 exchange patterns sit at the b64 4-lane/bank floor.
// Twiddles: direct table gathers (indices < 4096, no mask needed):
//   stage1: tw[16*hi*c] (uniform per 16-lane group -> broadcast)
//   stage2: tw[n1*(hi+16*c)] (L1-resident 32KB table gather)
__global__ __launch_bounds__(T, 5) void conv_fft(
    const float* __restrict__ xr, const float* __restrict__ xi,
    const float2* __restrict__ G, const float2* __restrict__ tw,
    float* __restrict__ out) {
  __shared__ float2 L[16 * 256];
  const int row = blockIdx.x;
  const int t = threadIdx.x;
  const int n1 = t & 15;
  const int hi = t >> 4;          // m1 in stage 1, j2 in stage 2
  const float* __restrict__ rr = xr + (size_t)row * NX;
  const float* __restrict__ ri = xi + (size_t)row * NX;

  float2 e[16], u[16];
#pragma unroll
  for (int m = 0; m < 4; ++m) e[m] = make_float2(rr[t + 256 * m], ri[t + 256 * m]);

  // ================= FORWARD =================
  dft16_sp4<1>(e, u);
#pragma unroll
  for (int c = 1; c < 16; ++c) u[c] = tmul<1>(u[c], tw[16 * hi * c]);
#pragma unroll
  for (int c = 0; c < 16; ++c) L[c * 256 + t] = u[c];             // write ex1
  __syncthreads();
#pragma unroll
  for (int m1 = 0; m1 < 16; ++m1) e[m1] = L[hi * 256 + m1 * 16 + n1];  // read ex1
  __syncthreads();
  dft16<1>(e, u);
#pragma unroll
  for (int c = 0; c < 16; ++c) u[c] = tmul<1>(u[c], tw[n1 * (hi + 16 * c)]);
#pragma unroll
  for (int j1 = 0; j1 < 16; ++j1)
    L[n1 * 256 + ((hi ^ n1) + 16 * j1)] = u[j1];                  // write ex2 (swz)
  __syncthreads();
#pragma unroll
  for (int q = 0; q < 16; ++q) e[q] = L[q * 256 + (t ^ q)];       // read ex2 (swz)
  dft16<1>(e, u);   // u[k1] = X[t + 256*k1]

  // ---- pointwise Z = X^2 * G' ----
#pragma unroll
  for (int k = 0; k < 16; ++k) {
    const float2 X = u[k];
    e[k] = cmulf(cmulf(X, X), G[t + 256 * k]);
  }
  __syncthreads();   // ex2 reads done before inverse reuses L

  // ================= INVERSE =================
  dft16<-1>(e, u);
#pragma unroll
  for (int c = 1; c < 16; ++c) u[c] = tmul<-1>(u[c], tw[16 * hi * c]);
#pragma unroll
  for (int c = 0; c < 16; ++c) L[c * 256 + t] = u[c];
  __syncthreads();
#pragma unroll
  for (int m1 = 0; m1 < 16; ++m1) e[m1] = L[hi * 256 + m1 * 16 + n1];
  __syncthreads();
  dft16<-1>(e, u);
#pragma unroll
  for (int c = 0; c < 16; ++c) u[c] = tmul<-1>(u[c], tw[n1 * (hi + 16 * c)]);
#pragma unroll
  for (int j1 = 0; j1 < 16; ++j1)
    L[n1 * 256 + ((hi ^ n1) + 16 * j1)] = u[j1];
  __syncthreads();
#pragma unroll
  for (int q = 0; q < 16; ++q) e[q] = L[q * 256 + (t ^ q)];
  dft16<-1>(e, u);   // u[k1] = y[t + 256*k1], scaled by 1/4096 via G'

  // ---- magnitude + crop [255, 2303) -> out[0, 2048) ----
  float* __restrict__ orow = out + (size_t)row * OUTN;
#pragma unroll
  for (int k = 1; k < 8; ++k) {
    const float2 y = u[k];
    orow[t + 256 * k - OFF] = sqrtf(y.x * y.x + y.y * y.y);
  }
  if (t == 255) { const float2 y = u[0]; orow[0] = sqrtf(y.x * y.x + y.y * y.y); }
  if (t < 255)  { const float2 y = u[8]; orow[1793 + t] = sqrtf(y.x * y.x + y.y * y.y); }
}

extern "C" void kernel_launch(void* const* d_in, const int* in_sizes, int n_in,
                              void* d_out, int out_size, void* d_ws, size_t ws_size,
                              hipStream_t stream) {
  const float* xr  = (const float*)d_in[0];
  const float* xi  = (const float*)d_in[1];
  const float* w0r = (const float*)d_in[2];
  const float* w0i = (const float*)d_in[3];
  const float* wlr = (const float*)d_in[4];
  const float* wli = (const float*)d_in[5];
  float* out = (float*)d_out;
  float2* G  = (float2*)d_ws;                                   // 4096 float2
  float2* tw = (float2*)((char*)d_ws + NFFT * sizeof(float2));  // 4096 float2
  hipLaunchKernelGGL(init_tables, dim3(16), dim3(256), 0, stream,
                     w0r, w0i, wlr, wli, G, tw);
  hipLaunchKernelGGL(conv_fft, dim3(ROWS), dim3(T), 0, stream,
                     xr, xi, G, tw, out);
}

// Round 12
// 146.463 us; speedup vs baseline: 2.1133x; 2.1133x over previous
//
#include <hip/hip_runtime.h>
#include <math.h>

#define NFFT 4096
#define T    256
#define ROWS 4096
#define NX   1024
#define OUTN 2048
#define OFF  255

__device__ __forceinline__ float2 cmulf(float2 a, float2 b) {
  return make_float2(a.x * b.x - a.y * b.y, a.x * b.y + a.y * b.x);
}
__device__ __forceinline__ float2 caddf(float2 a, float2 b) {
  return make_float2(a.x + b.x, a.y + b.y);
}
__device__ __forceinline__ float2 csubf(float2 a, float2 b) {
  return make_float2(a.x - b.x, a.y - b.y);
}
// multiply by -i (fwd) / +i (inv)
template <int DIR> __device__ __forceinline__ float2 mulmi(float2 a) {
  return (DIR > 0) ? make_float2(a.y, -a.x) : make_float2(-a.y, a.x);
}
// multiply by constant twiddle in FORWARD convention; conj for inverse
template <int DIR> __device__ __forceinline__ float2 cmulc(float2 a, float wr, float wi) {
  const float y = (DIR > 0) ? wi : -wi;
  return make_float2(a.x * wr - a.y * y, a.x * y + a.y * wr);
}

#define C16 0.9238795325112867f
#define S16 0.3826834323650898f
#define RH  0.7071067811865476f

// In-place 16-pt DFT: v[c] = sum_m v[m] W16^{mc} (conj for DIR=-1).
// Loop 1 reads ALL of v into f[] before loop 2 writes v -> in-place safe.
template <int DIR>
__device__ __forceinline__ void dft16(float2* v) {
  float2 f[16];
#pragma unroll
  for (int r = 0; r < 4; ++r) {
    const float2 a = v[r], b = v[r + 4], c = v[r + 8], d = v[r + 12];
    const float2 apc = caddf(a, c), amc = csubf(a, c);
    const float2 bpd = caddf(b, d), bmd = csubf(b, d);
    const float2 jb = mulmi<DIR>(bmd);
    f[r]      = caddf(apc, bpd);
    f[r + 4]  = caddf(amc, jb);
    f[r + 8]  = csubf(apc, bpd);
    f[r + 12] = csubf(amc, jb);
  }
  f[5]  = cmulc<DIR>(f[5],  C16, -S16);
  f[6]  = cmulc<DIR>(f[6],  RH,  -RH);
  f[7]  = cmulc<DIR>(f[7],  S16, -C16);
  f[9]  = cmulc<DIR>(f[9],  RH,  -RH);
  f[10] = mulmi<DIR>(f[10]);
  f[11] = cmulc<DIR>(f[11], -RH, -RH);
  f[13] = cmulc<DIR>(f[13], S16, -C16);
  f[14] = cmulc<DIR>(f[14], -RH, -RH);
  f[15] = cmulc<DIR>(f[15], -C16, S16);
#pragma unroll
  for (int c4 = 0; c4 < 4; ++c4) {
    const float2 a = f[4 * c4], b = f[4 * c4 + 1], c = f[4 * c4 + 2], d = f[4 * c4 + 3];
    const float2 apc = caddf(a, c), amc = csubf(a, c);
    const float2 bpd = caddf(b, d), bmd = csubf(b, d);
    const float2 jb = mulmi<DIR>(bmd);
    v[c4]      = caddf(apc, bpd);
    v[c4 + 4]  = caddf(amc, jb);
    v[c4 + 8]  = csubf(apc, bpd);
    v[c4 + 12] = csubf(amc, jb);
  }
}

// In-place 16-pt DFT with only v[0..3] nonzero; inputs copied to locals first.
template <int DIR>
__device__ __forceinline__ void dft16_sp4(float2* v) {
  const float2 v0 = v[0], v1 = v[1], v2 = v[2], v3 = v[3];
#pragma unroll
  for (int c4 = 0; c4 < 4; ++c4) {
    const float2 a = v0;
    const float2 b = (c4 == 0) ? v1
                   : (c4 == 1) ? cmulc<DIR>(v1, C16, -S16)
                   : (c4 == 2) ? cmulc<DIR>(v1, RH, -RH)
                               : cmulc<DIR>(v1, S16, -C16);
    const float2 c = (c4 == 0) ? v2
                   : (c4 == 1) ? cmulc<DIR>(v2, RH, -RH)
                   : (c4 == 2) ? mulmi<DIR>(v2)
                               : cmulc<DIR>(v2, -RH, -RH);
    const float2 d = (c4 == 0) ? v3
                   : (c4 == 1) ? cmulc<DIR>(v3, S16, -C16)
                   : (c4 == 2) ? cmulc<DIR>(v3, -RH, -RH)
                               : cmulc<DIR>(v3, -C16, S16);
    const float2 apc = caddf(a, c), amc = csubf(a, c);
    const float2 bpd = caddf(b, d), bmd = csubf(b, d);
    const float2 jb = mulmi<DIR>(bmd);
    v[c4]      = caddf(apc, bpd);
    v[c4 + 4]  = caddf(amc, jb);
    v[c4 + 8]  = csubf(apc, bpd);
    v[c4 + 12] = csubf(amc, jb);
  }
}

// u[c] *= step^c (u[0] untouched). Caller pre-conjugates step for inverse.
__device__ __forceinline__ void chain_apply(float2* u, float2 step) {
  float2 w = step;
  u[1] = cmulf(u[1], w);
#pragma unroll
  for (int c = 2; c < 16; ++c) { w = cmulf(w, step); u[c] = cmulf(u[c], w); }
}
// u[c] *= base * step^c.
__device__ __forceinline__ void chain_apply_base(float2* u, float2 base, float2 step) {
  float2 w = base;
  u[0] = cmulf(u[0], w);
#pragma unroll
  for (int c = 1; c < 16; ++c) { w = cmulf(w, step); u[c] = cmulf(u[c], w); }
}

// Init: G[f] = W0(f)^2 * WL(f) / 4096; tw[n] = exp(-2*pi*i*n/4096), n < 4096.
__global__ __launch_bounds__(256) void init_tables(
    const float* __restrict__ w0r, const float* __restrict__ w0i,
    const float* __restrict__ wlr, const float* __restrict__ wli,
    float2* __restrict__ G, float2* __restrict__ tw) {
  const int f = blockIdx.x * blockDim.x + threadIdx.x;
  if (f >= NFFT) return;
  const float cconst = -2.0f * 3.14159265358979323846f / (float)NFFT;
  float w0re = 0.f, w0im = 0.f;
  for (int n = 0; n < 129; ++n) {
    const int mfn = (f * n) & (NFFT - 1);
    float sv, cv;
    __sincosf(cconst * (float)mfn, &sv, &cv);
    const float ar = w0r[n], ai = w0i[n];
    w0re += ar * cv - ai * sv;
    w0im += ar * sv + ai * cv;
  }
  float wlre = 0.f, wlim = 0.f;
  for (int n = 0; n < 257; ++n) {
    const int mfn = (f * n) & (NFFT - 1);
    float sv, cv;
    __sincosf(cconst * (float)mfn, &sv, &cv);
    const float ar = wlr[n], ai = wli[n];
    wlre += ar * cv - ai * sv;
    wlim += ar * sv + ai * cv;
  }
  const float2 W0 = make_float2(w0re, w0im);
  const float2 WL = make_float2(wlre, wlim);
  const float2 g = cmulf(cmulf(W0, W0), WL);
  G[f] = make_float2(g.x * (1.0f / NFFT), g.y * (1.0f / NFFT));
  float sv, cv;
  __sincosf(cconst * (float)f, &sv, &cv);
  tw[f] = make_float2(cv, sv);
}

// Register-resident 16^3 FFT, in-place on ONE e[16] array (peak pressure
// e[16]+f[16] ~ 64 regs + temps). Chain twiddles (measured-good, round 6).
// XOR-swizzled ex2 -> LDS = 32768 B exactly (HW-validated: 0 conflicts).
// __launch_bounds__(T,4): VGPR cap 128; if allocator lands <=102, HW can
// still co-schedule 5 blocks/CU (LDS allows 5).
__global__ __launch_bounds__(T, 4) void conv_fft(
    const float* __restrict__ xr, const float* __restrict__ xi,
    const float2* __restrict__ G, const float2* __restrict__ tw,
    float* __restrict__ out) {
  __shared__ float2 L[16 * 256];
  const int row = blockIdx.x;
  const int t = threadIdx.x;
  const int n1 = t & 15;
  const int hi = t >> 4;          // m1 in stage 1, j2 in stage 2
  const float* __restrict__ rr = xr + (size_t)row * NX;
  const float* __restrict__ ri = xi + (size_t)row * NX;

  float2 e[16];
#pragma unroll
  for (int m = 0; m < 4; ++m) e[m] = make_float2(rr[t + 256 * m], ri[t + 256 * m]);

  // ================= FORWARD =================
  dft16_sp4<1>(e);
  chain_apply(e, tw[16 * hi]);                                  // W256^{m1 c}
#pragma unroll
  for (int c = 0; c < 16; ++c) L[c * 256 + t] = e[c];           // write ex1
  __syncthreads();
#pragma unroll
  for (int m1 = 0; m1 < 16; ++m1) e[m1] = L[hi * 256 + m1 * 16 + n1];  // read ex1
  __syncthreads();
  dft16<1>(e);
  { float2 b2 = tw[n1 * hi]; float2 s2 = tw[16 * n1];
    chain_apply_base(e, b2, s2); }                              // W4096^{n1(j2+16j1)}
#pragma unroll
  for (int j1 = 0; j1 < 16; ++j1)
    L[n1 * 256 + ((hi ^ n1) + 16 * j1)] = e[j1];                // write ex2 (swz)
  __syncthreads();
#pragma unroll
  for (int q = 0; q < 16; ++q) e[q] = L[q * 256 + (t ^ q)];     // read ex2 (swz)
  dft16<1>(e);   // e[k1] = X[t + 256*k1]

  // ---- pointwise Z = X^2 * G' (G' includes 1/4096) ----
#pragma unroll
  for (int k = 0; k < 16; ++k) {
    const float2 X = e[k];
    e[k] = cmulf(cmulf(X, X), G[t + 256 * k]);
  }
  __syncthreads();   // ex2 reads done before inverse reuses L

  // ================= INVERSE (conjugated twiddles) =================
  dft16<-1>(e);
  { float2 s1 = tw[16 * hi]; s1.y = -s1.y; chain_apply(e, s1); }
#pragma unroll
  for (int c = 0; c < 16; ++c) L[c * 256 + t] = e[c];
  __syncthreads();
#pragma unroll
  for (int m1 = 0; m1 < 16; ++m1) e[m1] = L[hi * 256 + m1 * 16 + n1];
  __syncthreads();
  dft16<-1>(e);
  { float2 b2 = tw[n1 * hi]; b2.y = -b2.y;
    float2 s2 = tw[16 * n1]; s2.y = -s2.y; chain_apply_base(e, b2, s2); }
#pragma unroll
  for (int j1 = 0; j1 < 16; ++j1)
    L[n1 * 256 + ((hi ^ n1) + 16 * j1)] = e[j1];
  __syncthreads();
#pragma unroll
  for (int q = 0; q < 16; ++q) e[q] = L[q * 256 + (t ^ q)];
  dft16<-1>(e);   // e[k1] = y[t + 256*k1] (1/4096 folded in G')

  // ---- magnitude + crop [255, 2303) -> out[0, 2048) ----
  float* __restrict__ orow = out + (size_t)row * OUTN;
#pragma unroll
  for (int k = 1; k < 8; ++k) {
    const float2 y = e[k];
    orow[t + 256 * k - OFF] = sqrtf(y.x * y.x + y.y * y.y);
  }
  if (t == 255) { const float2 y = e[0]; orow[0] = sqrtf(y.x * y.x + y.y * y.y); }
  if (t < 255)  { const float2 y = e[8]; orow[1793 + t] = sqrtf(y.x * y.x + y.y * y.y); }
}

extern "C" void kernel_launch(void* const* d_in, const int* in_sizes, int n_in,
                              void* d_out, int out_size, void* d_ws, size_t ws_size,
                              hipStream_t stream) {
  const float* xr  = (const float*)d_in[0];
  const float* xi  = (const float*)d_in[1];
  const float* w0r = (const float*)d_in[2];
  const float* w0i = (const float*)d_in[3];
  const float* wlr = (const float*)d_in[4];
  const float* wli = (const float*)d_in[5];
  float* out = (float*)d_out;
  float2* G  = (float2*)d_ws;                                   // 4096 float2
  float2* tw = (float2*)((char*)d_ws + NFFT * sizeof(float2));  // 4096 float2
  hipLaunchKernelGGL(init_tables, dim3(16), dim3(256), 0, stream,
                     w0r, w0i, wlr, wli, G, tw);
  hipLaunchKernelGGL(conv_fft, dim3(ROWS), dim3(T), 0, stream,
                     xr, xi, G, tw, out);
}